// Round 12
// baseline (298.726 us; speedup 1.0000x reference)
//
#include <hip/hip_runtime.h>

#define NN 50000     // nodes
#define NE 800000    // edges
#define DD 64        // channels
#define NG 512       // graphs

// ---------------- session ledger ----------------
// R11: CSR v3 fixed-capacity bucket sort (CAP=1280, +8 sigma) — kept.
// R12: layer fusion REVERTED (occupancy collapse starved gather).
// R13-R15: quartering/XCD-pin REVERTED (broadcast floor, overheads).
// R16-R18: bf16 gather WIN; bf16 convert must stay OUT of VALU-dense.
// R19/R20: request-halving NEUTRAL -> gather not request-bound.
// R21: MFMA bf16 dense WIN (291 us; dense ~8 us/layer, to_bf16 gone).
// R22 (this round): last untested gather theory — outstanding-miss
//   (MSHR) parallelism. 2 nodes/wave -> 4-8 gathers in flight (was 2-4)
//   at unchanged occupancy (~48 VGPR, no LDS; NOT R12's fusion).
//   Neutral result would pin gather at compulsory-broadcast service
//   floor (all theories then exhausted).

#define BSH 6
#define NBU ((NN + 63) >> BSH)          // 782
#define CAP 1280                        // bucket capacity (mean 1023, sigma 32)
#define EPB 8192                        // edges per block in scatter
#define NBLK ((NE + EPB - 1) / EPB)     // 98

typedef __attribute__((ext_vector_type(8))) short bf16x8;
typedef __attribute__((ext_vector_type(4))) float f32x4;

__global__ void bucket_scatter_k(const int* __restrict__ src, const int* __restrict__ dst,
                                 int* __restrict__ bcur, int* __restrict__ ebuf) {
    __shared__ int hist[NBU];
    __shared__ int base[NBU];
    for (int i = threadIdx.x; i < NBU; i += 256) hist[i] = 0;
    __syncthreads();
    int e0 = blockIdx.x * EPB;
    int e1 = min(e0 + EPB, NE);
    for (int e = e0 + threadIdx.x; e < e1; e += 256)
        atomicAdd(&hist[dst[e] >> BSH], 1);
    __syncthreads();
    for (int i = threadIdx.x; i < NBU; i += 256) {
        int c = hist[i];
        base[i] = c ? (i * CAP + atomicAdd(&bcur[i], c)) : 0;
        hist[i] = 0;
    }
    __syncthreads();
    for (int e = e0 + threadIdx.x; e < e1; e += 256) {
        int s = src[e];
        int d = dst[e];
        int b = d >> BSH;
        int r = atomicAdd(&hist[b], 1);
        ebuf[base[b] + r] = (s << 6) | (d & 63);
    }
}

__global__ void bucket_finalize_k(const int* __restrict__ ebuf, const int* __restrict__ bcur,
                                  int* __restrict__ deg, int* __restrict__ start,
                                  int* __restrict__ col) {
    __shared__ int dcnt[64];
    __shared__ int dstart[64];
    const int b = blockIdx.x;
    const int t = threadIdx.x;
    const int e0 = b * CAP;
    const int n = bcur[b];
    if (t < 64) dcnt[t] = 0;
    __syncthreads();
    for (int i = t; i < n; i += 256)
        atomicAdd(&dcnt[ebuf[e0 + i] & 63], 1);
    __syncthreads();
    if (t < 64) {   // wave 0: 64-entry exclusive scan
        int v = dcnt[t];
        int incl = v;
#pragma unroll
        for (int off = 1; off < 64; off <<= 1) {
            int u = __shfl_up(incl, off, 64);
            if (t >= off) incl += u;
        }
        dstart[t] = e0 + incl - v;
        int node = (b << BSH) + t;
        if (node < NN) { deg[node] = v; start[node] = e0 + incl - v; }
        dcnt[t] = 0;
    }
    __syncthreads();
    for (int i = t; i < n; i += 256) {
        int v = ebuf[e0 + i];
        int ln = v & 63;
        int r = atomicAdd(&dcnt[ln], 1);
        col[dstart[ln] + r] = v >> 6;
    }
}

// ---------------- bf16 helpers ----------------

__device__ __forceinline__ unsigned bf16rne(float f) {
    unsigned u = __float_as_uint(f);
    return (u + 0x7FFFu + ((u >> 16) & 1u)) >> 16;
}

__device__ __forceinline__ void accb2(float& a, float& b, unsigned v) {
    a += __uint_as_float(v << 16);
    b += __uint_as_float(v & 0xFFFF0000u);
}
__device__ __forceinline__ void accb8(float4& a0, float4& a1, uint4 v) {
    accb2(a0.x, a0.y, v.x);
    accb2(a0.z, a0.w, v.y);
    accb2(a1.x, a1.y, v.z);
    accb2(a1.z, a1.w, v.w);
}

// expand 4 packed bf16 (uint2) -> float4
__device__ __forceinline__ float4 expb(uint2 v) {
    float4 r;
    r.x = __uint_as_float(v.x << 16);
    r.y = __uint_as_float(v.x & 0xFFFF0000u);
    r.z = __uint_as_float(v.y << 16);
    r.w = __uint_as_float(v.y & 0xFFFF0000u);
    return r;
}

__global__ void to_bf16_k(const float* __restrict__ in, ushort* __restrict__ outb) {
    int i = blockIdx.x * blockDim.x + threadIdx.x;   // one float4 -> uint2
    if (i < NN * DD / 4) {
        float4 v = ((const float4*)in)[i];
        uint2 w;
        w.x = bf16rne(v.x) | (bf16rne(v.y) << 16);
        w.y = bf16rne(v.z) | (bf16rne(v.w) << 16);
        ((uint2*)outb)[i] = w;
    }
}

// weights -> bf16 concat wcat[l][o][k]: k<64 from rel_w, k>=64 from root_w
__global__ void cvt_w_k(const float* __restrict__ rel_w, const float* __restrict__ root_w,
                        ushort* __restrict__ wcat) {
    int i = blockIdx.x * blockDim.x + threadIdx.x;
    if (i < 5 * 64 * 128) {
        int k = i & 127;
        int o = (i >> 7) & 63;
        int l = i >> 13;
        float v = (k < 64) ? rel_w[l * 4096 + o * 64 + k]
                           : root_w[l * 4096 + o * 64 + (k - 64)];
        wcat[i] = (ushort)bf16rne(v);
    }
}

// ---------------- aggregation v10: bf16, 16B requests, 2 nodes/wave ----------------
// lanes = 8 edge-groups x 8 channel-octs; wave handles nodes 2w, 2w+1
// interleaved -> 4-8 independent uint4 gathers in flight before any use
// (R22: MSHR-parallelism probe). Per-node accumulation order identical
// to v9 -> bitwise-same results.
__global__ void aggregate_b_k(const ushort* __restrict__ hb, const int* __restrict__ start,
                              const int* __restrict__ deg, const int* __restrict__ col,
                              ushort* __restrict__ aggb) {
    int pw = (blockIdx.x * blockDim.x + threadIdx.x) >> 6;   // pair index
    int lane = threadIdx.x & 63;
    int nA = pw * 2;
    if (nA >= NN) return;
    int nB = nA + 1;
    bool hasB = (nB < NN);
    int eg = lane >> 3;   // edge group 0..7
    int oc = lane & 7;    // channel oct
    int li = lane & 31;   // chunk position
    const int sA = start[nA], dA = deg[nA];
    const int sB = hasB ? start[nB] : 0;
    const int dB = hasB ? deg[nB] : 0;
    float4 aA0 = make_float4(0.f, 0.f, 0.f, 0.f), aA1 = make_float4(0.f, 0.f, 0.f, 0.f);
    float4 aB0 = make_float4(0.f, 0.f, 0.f, 0.f), aB1 = make_float4(0.f, 0.f, 0.f, 0.f);
    const uint4* h4b = (const uint4*)hb;   // row stride = 8 uint4 = 128 B
    const int dmx = max(dA, dB);           // wave-uniform
    for (int base = 0; base < dmx; base += 32) {
        const int cntA = dA - base, cntB = dB - base;
        const bool okA = (cntA > 0), okB = (cntB > 0);   // wave-uniform
        const bool hiA = (cntA > 16), hiB = (cntB > 16);
        int cA = 0, cB = 0;
        if (okA) cA = col[sA + min(base + li, dA - 1)];
        if (okB) cB = col[sB + min(base + li, dB - 1)];
        uint4 vA0, vA1, vA2, vA3, vB0, vB1, vB2, vB3;
        if (okA) {
            int n0 = __shfl(cA, eg + 0, 64);
            int n1 = __shfl(cA, eg + 8, 64);
            vA0 = h4b[(size_t)n0 * 8 + oc];
            vA1 = h4b[(size_t)n1 * 8 + oc];
        }
        if (okB) {
            int n0 = __shfl(cB, eg + 0, 64);
            int n1 = __shfl(cB, eg + 8, 64);
            vB0 = h4b[(size_t)n0 * 8 + oc];
            vB1 = h4b[(size_t)n1 * 8 + oc];
        }
        if (hiA) {
            int n2 = __shfl(cA, eg + 16, 64);
            int n3 = __shfl(cA, eg + 24, 64);
            vA2 = h4b[(size_t)n2 * 8 + oc];
            vA3 = h4b[(size_t)n3 * 8 + oc];
        }
        if (hiB) {
            int n2 = __shfl(cB, eg + 16, 64);
            int n3 = __shfl(cB, eg + 24, 64);
            vB2 = h4b[(size_t)n2 * 8 + oc];
            vB3 = h4b[(size_t)n3 * 8 + oc];
        }
        if (okA) {
            if (eg + 0 < cntA) accb8(aA0, aA1, vA0);
            if (eg + 8 < cntA) accb8(aA0, aA1, vA1);
            if (hiA) {
                if (eg + 16 < cntA) accb8(aA0, aA1, vA2);
                if (eg + 24 < cntA) accb8(aA0, aA1, vA3);
            }
        }
        if (okB) {
            if (eg + 0 < cntB) accb8(aB0, aB1, vB0);
            if (eg + 8 < cntB) accb8(aB0, aB1, vB1);
            if (hiB) {
                if (eg + 16 < cntB) accb8(aB0, aB1, vB2);
                if (eg + 24 < cntB) accb8(aB0, aB1, vB3);
            }
        }
    }
    // reduce over 8 edge groups (eg = lane bits 3..5): xor 8,16,32
#pragma unroll
    for (int off = 8; off <= 32; off <<= 1) {
        aA0.x += __shfl_xor(aA0.x, off, 64);
        aA0.y += __shfl_xor(aA0.y, off, 64);
        aA0.z += __shfl_xor(aA0.z, off, 64);
        aA0.w += __shfl_xor(aA0.w, off, 64);
        aA1.x += __shfl_xor(aA1.x, off, 64);
        aA1.y += __shfl_xor(aA1.y, off, 64);
        aA1.z += __shfl_xor(aA1.z, off, 64);
        aA1.w += __shfl_xor(aA1.w, off, 64);
        aB0.x += __shfl_xor(aB0.x, off, 64);
        aB0.y += __shfl_xor(aB0.y, off, 64);
        aB0.z += __shfl_xor(aB0.z, off, 64);
        aB0.w += __shfl_xor(aB0.w, off, 64);
        aB1.x += __shfl_xor(aB1.x, off, 64);
        aB1.y += __shfl_xor(aB1.y, off, 64);
        aB1.z += __shfl_xor(aB1.z, off, 64);
        aB1.w += __shfl_xor(aB1.w, off, 64);
    }
    if (eg == 0) {
        uint4 wv;
        wv.x = bf16rne(aA0.x) | (bf16rne(aA0.y) << 16);
        wv.y = bf16rne(aA0.z) | (bf16rne(aA0.w) << 16);
        wv.z = bf16rne(aA1.x) | (bf16rne(aA1.y) << 16);
        wv.w = bf16rne(aA1.z) | (bf16rne(aA1.w) << 16);
        ((uint4*)(aggb + (size_t)nA * DD))[oc] = wv;
        if (hasB) {
            uint4 wb;
            wb.x = bf16rne(aB0.x) | (bf16rne(aB0.y) << 16);
            wb.y = bf16rne(aB0.z) | (bf16rne(aB0.w) << 16);
            wb.z = bf16rne(aB1.x) | (bf16rne(aB1.y) << 16);
            wb.w = bf16rne(aB1.z) | (bf16rne(aB1.w) << 16);
            ((uint4*)(aggb + (size_t)nB * DD))[oc] = wb;
        }
    }
}

// ---------------- dense layer v6: MFMA bf16 GEMM (proven R21) ----------------
// C[64 nodes][64 out] = X[64][128] @ wcat_l^T, X = [aggb | hbin] bf16.
// block = 256 = 4 waves; wave wr owns 16-node slab, 4 out-tiles x 4
// K-steps of mfma_f32_16x16x32_bf16; LDS epilogue bias+resid+relu.
template <int RESID, int LAST>
__global__ void __launch_bounds__(256, 4)
dense_mfma_k(const ushort* __restrict__ aggb, const ushort* __restrict__ hbin,
             const ushort* __restrict__ wcat, const float* __restrict__ brel,
             ushort* __restrict__ hbout, float* __restrict__ houtf) {
    __shared__ float Cs[64][68];
    const int t = threadIdx.x;
    const int lane = t & 63;
    const int wr = t >> 6;            // wave id = node-slab 0..3
    const int tile = blockIdx.x * 64;
    const int nrows = min(64, NN - tile);

    const int r16 = lane & 15;        // A row in slab / B out-col in tile
    const int kg = lane >> 4;         // k-group 0..3 (8 contiguous k)

    const size_t node = (size_t)(tile + wr * 16 + r16);   // may pad-read past NN
    bf16x8 a0 = *(const bf16x8*)(aggb + node * DD +  0 + kg * 8);
    bf16x8 a1 = *(const bf16x8*)(aggb + node * DD + 32 + kg * 8);
    bf16x8 a2 = *(const bf16x8*)(hbin + node * DD +  0 + kg * 8);
    bf16x8 a3 = *(const bf16x8*)(hbin + node * DD + 32 + kg * 8);

#pragma unroll
    for (int oc = 0; oc < 4; ++oc) {
        const ushort* wrow = wcat + (size_t)(oc * 16 + r16) * 128 + kg * 8;
        bf16x8 b0 = *(const bf16x8*)(wrow + 0);
        bf16x8 b1 = *(const bf16x8*)(wrow + 32);
        bf16x8 b2 = *(const bf16x8*)(wrow + 64);
        bf16x8 b3 = *(const bf16x8*)(wrow + 96);
        f32x4 c = {0.f, 0.f, 0.f, 0.f};
        c = __builtin_amdgcn_mfma_f32_16x16x32_bf16(a0, b0, c, 0, 0, 0);
        c = __builtin_amdgcn_mfma_f32_16x16x32_bf16(a1, b1, c, 0, 0, 0);
        c = __builtin_amdgcn_mfma_f32_16x16x32_bf16(a2, b2, c, 0, 0, 0);
        c = __builtin_amdgcn_mfma_f32_16x16x32_bf16(a3, b3, c, 0, 0, 0);
        float bias = brel[oc * 16 + r16];
#pragma unroll
        for (int r = 0; r < 4; ++r)
            Cs[wr * 16 + kg * 4 + r][oc * 16 + r16] = c[r] + bias;
    }
    __syncthreads();

    const uint2* hbin2 = (const uint2*)hbin + (size_t)tile * 16;   // row = 16 uint2
    uint2* outb2 = (uint2*)hbout + (size_t)tile * 16;
    float4* out4 = (float4*)(houtf + (size_t)tile * DD);
#pragma unroll
    for (int k = 0; k < 4; ++k) {
        int idx = t + k * 256;
        int row = idx >> 4, cq = idx & 15;
        if (row < nrows) {
            float4 r = *(const float4*)&Cs[row][4 * cq];
            if (RESID) {
                float4 hv = expb(hbin2[idx]);
                r.x += hv.x; r.y += hv.y; r.z += hv.z; r.w += hv.w;
            }
            r.x = fmaxf(r.x, 0.f); r.y = fmaxf(r.y, 0.f);
            r.z = fmaxf(r.z, 0.f); r.w = fmaxf(r.w, 0.f);
            uint2 wb;
            wb.x = bf16rne(r.x) | (bf16rne(r.y) << 16);
            wb.y = bf16rne(r.z) | (bf16rne(r.w) << 16);
            outb2[idx] = wb;
            if (LAST) out4[idx] = r;
        }
    }
}

// ---------------- pooling (batch is sorted) ----------------

__global__ void pool_k(const float* __restrict__ h, const int* __restrict__ batch,
                       float* __restrict__ sums, int* __restrict__ cnt) {
    const int NP = 32;
    int w = (blockIdx.x * blockDim.x + threadIdx.x) >> 6;
    int lane = threadIdx.x & 63;
    int n0 = w * NP;
    if (n0 >= NN) return;
    int n1 = min(n0 + NP, NN);
    int g = batch[n0];
    float acc = 0.f;
    int run = 0;
    for (int i = n0; i < n1; ++i) {
        int gi = batch[i];
        if (gi != g) {
            atomicAdd(&sums[g * DD + lane], acc);
            if (lane == 0) atomicAdd(&cnt[g], run);
            acc = 0.f; run = 0; g = gi;
        }
        acc += h[i * DD + lane];
        run++;
    }
    atomicAdd(&sums[g * DD + lane], acc);
    if (lane == 0) atomicAdd(&cnt[g], run);
}

// ---------------- head: mean -> linear -> softmax ----------------

__global__ void head_k(const float* __restrict__ sums, const int* __restrict__ cnt,
                       const float* __restrict__ lin_w, const float* __restrict__ lin_b,
                       float* __restrict__ out) {
    int g = blockIdx.x * (blockDim.x >> 6) + (threadIdx.x >> 6);
    int o = threadIdx.x & 63;
    if (g >= NG) return;
    float c = (float)cnt[g];
    float inv = 1.0f / fmaxf(c, 1.0f);
    float acc = lin_b[o];
#pragma unroll 8
    for (int k = 0; k < DD; ++k) {
        acc += sums[g * DD + k] * inv * lin_w[o * DD + k];
    }
    float m = acc;
#pragma unroll
    for (int off = 32; off; off >>= 1) m = fmaxf(m, __shfl_xor(m, off, 64));
    float e = __expf(acc - m);
    float s = e;
#pragma unroll
    for (int off = 32; off; off >>= 1) s += __shfl_xor(s, off, 64);
    out[g * DD + o] = e / s;
}

// ---------------- driver ----------------

extern "C" void kernel_launch(void* const* d_in, const int* in_sizes, int n_in,
                              void* d_out, int out_size, void* d_ws, size_t ws_size,
                              hipStream_t stream) {
    const float* x      = (const float*)d_in[0];
    const int*   edge   = (const int*)d_in[1];   // [2, E]: src = edge, dst = edge+NE
    const int*   batch  = (const int*)d_in[2];
    const float* rel_w  = (const float*)d_in[3]; // [L, D, D]
    const float* rel_b  = (const float*)d_in[4]; // [L, D]
    const float* root_w = (const float*)d_in[5]; // [L, D, D]
    const float* lin_w  = (const float*)d_in[6]; // [D, D]
    const float* lin_b  = (const float*)d_in[7]; // [D]
    float* out = (float*)d_out;

    const int* src = edge;
    const int* dst = edge + NE;

    // workspace carve (all 256B aligned)
    char* p = (char*)d_ws;
    auto carve = [&](size_t bytes) {
        char* r = p;
        p += (bytes + 255) & ~(size_t)255;
        return (void*)r;
    };
    const size_t PADROWS = 64;   // frag-load overrun guard for last block
    float*  hAf  = (float*)carve((size_t)NN * DD * 4);                    // fp32 final (pool)
    ushort* xb   = (ushort*)carve((size_t)(NN + PADROWS) * DD * 2);       // bf16 ping
    ushort* hb   = (ushort*)carve((size_t)(NN + PADROWS) * DD * 2);       // bf16 pong
    ushort* aggb = (ushort*)carve((size_t)(NN + PADROWS) * DD * 2);       // bf16 aggregate
    ushort* wcat = (ushort*)carve((size_t)5 * 64 * 128 * 2);              // bf16 weights
    int*    col  = (int*)carve((size_t)NBU * CAP * 4);   // 4.0 MB, bucket gaps unread
    int*    ebuf = (int*)carve((size_t)NBU * CAP * 4);   // 4.0 MB packed (src<<6)|dlow
    int*    strt = (int*)carve((size_t)NN * 4);
    int*    deg  = (int*)carve((size_t)NN * 4);
    // ---- contiguous zero region (single memset) ----
    char* zbase = p;
    float* sums = (float*)carve((size_t)NG * DD * 4);
    int*   cnt  = (int*)carve((size_t)NG * 4);
    int*   bcur = (int*)carve((size_t)NBU * 4);
    size_t zbytes = (size_t)(p - zbase);

    (void)hipMemsetAsync(zbase, 0, zbytes, stream);

    const int cvtBlocks = (NN * DD / 4 + 255) / 256;

    // conversions + CSR build v3
    to_bf16_k<<<cvtBlocks, 256, 0, stream>>>(x, xb);
    cvt_w_k<<<(5 * 64 * 128 + 255) / 256, 256, 0, stream>>>(rel_w, root_w, wcat);
    bucket_scatter_k<<<NBLK, 256, 0, stream>>>(src, dst, bcur, ebuf);
    bucket_finalize_k<<<NBU, 256, 0, stream>>>(ebuf, bcur, deg, strt, col);

    const int aggBlocks = ((NN + 1) / 2 + 3) / 4;   // 2 nodes/wave, 4 waves/block
    const int dnsBlocks = (NN + 63) / 64;           // 64 nodes per block

    // layer 0: gather xb -> aggb; mfma-dense -> hb
    aggregate_b_k<<<aggBlocks, 256, 0, stream>>>(xb, strt, deg, col, aggb);
    dense_mfma_k<0, 0><<<dnsBlocks, 256, 0, stream>>>(aggb, xb, wcat, rel_b, hb, hAf);
    // layer 1: gather hb -> aggb; dense -> xb
    aggregate_b_k<<<aggBlocks, 256, 0, stream>>>(hb, strt, deg, col, aggb);
    dense_mfma_k<0, 0><<<dnsBlocks, 256, 0, stream>>>(aggb, hb, wcat + 8192, rel_b + 64,
                                                      xb, hAf);
    // layer 2: gather xb; dense -> hb
    aggregate_b_k<<<aggBlocks, 256, 0, stream>>>(xb, strt, deg, col, aggb);
    dense_mfma_k<0, 0><<<dnsBlocks, 256, 0, stream>>>(aggb, xb, wcat + 2 * 8192,
                                                      rel_b + 2 * 64, hb, hAf);
    // layer 3 (residual): gather hb; dense -> xb
    aggregate_b_k<<<aggBlocks, 256, 0, stream>>>(hb, strt, deg, col, aggb);
    dense_mfma_k<1, 0><<<dnsBlocks, 256, 0, stream>>>(aggb, hb, wcat + 3 * 8192,
                                                      rel_b + 3 * 64, xb, hAf);
    // layer 4 (residual, LAST): gather xb; dense -> hb + fp32 hAf for pool
    aggregate_b_k<<<aggBlocks, 256, 0, stream>>>(xb, strt, deg, col, aggb);
    dense_mfma_k<1, 1><<<dnsBlocks, 256, 0, stream>>>(aggb, xb, wcat + 4 * 8192,
                                                      rel_b + 4 * 64, hb, hAf);

    // pool + head
    const int wavesPool = (NN + 31) / 32;
    pool_k<<<(wavesPool + 3) / 4, 256, 0, stream>>>(hAf, batch, sums, cnt);
    head_k<<<(NG + 3) / 4, 256, 0, stream>>>(sums, cnt, lin_w, lin_b, out);
}

// Round 14
// 289.693 us; speedup vs baseline: 1.0312x; 1.0312x over previous
//
#include <hip/hip_runtime.h>

#define NN 50000     // nodes
#define NE 800000    // edges
#define DD 64        // channels
#define NG 512       // graphs

// ---------------- session ledger ----------------
// R11: CSR v3 fixed-capacity bucket sort (CAP=1280, +8 sigma) — kept.
// R12: layer fusion REVERTED (occupancy collapse starved gather).
// R13-R15: quartering/XCD-pin REVERTED (broadcast floor, overheads).
// R16-R18: bf16 gather WIN; bf16 convert must stay OUT of VALU-dense.
// R19/R20: request-halving NEUTRAL -> gather not request-bound.
// R21: MFMA bf16 dense WIN (291 us; dense ~8 us/layer, to_bf16 gone).
// R22: MSHR probe (2 nodes/wave) NEUTRAL (298.7) -> gather pinned at
//   compulsory-broadcast L3 service floor. ALL gather theories exhausted
//   (bytes/requests/blocking/MSHR).
// R23/R24: terminal version = R21 exact (verified 291.2 us in R11).
//   R23 submission hit container-infra failure (no kernel verdict);
//   R24 is an unchanged resubmit.

#define BSH 6
#define NBU ((NN + 63) >> BSH)          // 782
#define CAP 1280                        // bucket capacity (mean 1023, sigma 32)
#define EPB 8192                        // edges per block in scatter
#define NBLK ((NE + EPB - 1) / EPB)     // 98

typedef __attribute__((ext_vector_type(8))) short bf16x8;
typedef __attribute__((ext_vector_type(4))) float f32x4;

__global__ void bucket_scatter_k(const int* __restrict__ src, const int* __restrict__ dst,
                                 int* __restrict__ bcur, int* __restrict__ ebuf) {
    __shared__ int hist[NBU];
    __shared__ int base[NBU];
    for (int i = threadIdx.x; i < NBU; i += 256) hist[i] = 0;
    __syncthreads();
    int e0 = blockIdx.x * EPB;
    int e1 = min(e0 + EPB, NE);
    for (int e = e0 + threadIdx.x; e < e1; e += 256)
        atomicAdd(&hist[dst[e] >> BSH], 1);
    __syncthreads();
    for (int i = threadIdx.x; i < NBU; i += 256) {
        int c = hist[i];
        base[i] = c ? (i * CAP + atomicAdd(&bcur[i], c)) : 0;
        hist[i] = 0;
    }
    __syncthreads();
    for (int e = e0 + threadIdx.x; e < e1; e += 256) {
        int s = src[e];
        int d = dst[e];
        int b = d >> BSH;
        int r = atomicAdd(&hist[b], 1);
        ebuf[base[b] + r] = (s << 6) | (d & 63);
    }
}

__global__ void bucket_finalize_k(const int* __restrict__ ebuf, const int* __restrict__ bcur,
                                  int* __restrict__ deg, int* __restrict__ start,
                                  int* __restrict__ col) {
    __shared__ int dcnt[64];
    __shared__ int dstart[64];
    const int b = blockIdx.x;
    const int t = threadIdx.x;
    const int e0 = b * CAP;
    const int n = bcur[b];
    if (t < 64) dcnt[t] = 0;
    __syncthreads();
    for (int i = t; i < n; i += 256)
        atomicAdd(&dcnt[ebuf[e0 + i] & 63], 1);
    __syncthreads();
    if (t < 64) {   // wave 0: 64-entry exclusive scan
        int v = dcnt[t];
        int incl = v;
#pragma unroll
        for (int off = 1; off < 64; off <<= 1) {
            int u = __shfl_up(incl, off, 64);
            if (t >= off) incl += u;
        }
        dstart[t] = e0 + incl - v;
        int node = (b << BSH) + t;
        if (node < NN) { deg[node] = v; start[node] = e0 + incl - v; }
        dcnt[t] = 0;
    }
    __syncthreads();
    for (int i = t; i < n; i += 256) {
        int v = ebuf[e0 + i];
        int ln = v & 63;
        int r = atomicAdd(&dcnt[ln], 1);
        col[dstart[ln] + r] = v >> 6;
    }
}

// ---------------- bf16 helpers ----------------

__device__ __forceinline__ unsigned bf16rne(float f) {
    unsigned u = __float_as_uint(f);
    return (u + 0x7FFFu + ((u >> 16) & 1u)) >> 16;
}

__device__ __forceinline__ void accb2(float& a, float& b, unsigned v) {
    a += __uint_as_float(v << 16);
    b += __uint_as_float(v & 0xFFFF0000u);
}
__device__ __forceinline__ void accb8(float4& a0, float4& a1, uint4 v) {
    accb2(a0.x, a0.y, v.x);
    accb2(a0.z, a0.w, v.y);
    accb2(a1.x, a1.y, v.z);
    accb2(a1.z, a1.w, v.w);
}

// expand 4 packed bf16 (uint2) -> float4
__device__ __forceinline__ float4 expb(uint2 v) {
    float4 r;
    r.x = __uint_as_float(v.x << 16);
    r.y = __uint_as_float(v.x & 0xFFFF0000u);
    r.z = __uint_as_float(v.y << 16);
    r.w = __uint_as_float(v.y & 0xFFFF0000u);
    return r;
}

__global__ void to_bf16_k(const float* __restrict__ in, ushort* __restrict__ outb) {
    int i = blockIdx.x * blockDim.x + threadIdx.x;   // one float4 -> uint2
    if (i < NN * DD / 4) {
        float4 v = ((const float4*)in)[i];
        uint2 w;
        w.x = bf16rne(v.x) | (bf16rne(v.y) << 16);
        w.y = bf16rne(v.z) | (bf16rne(v.w) << 16);
        ((uint2*)outb)[i] = w;
    }
}

// weights -> bf16 concat wcat[l][o][k]: k<64 from rel_w, k>=64 from root_w
__global__ void cvt_w_k(const float* __restrict__ rel_w, const float* __restrict__ root_w,
                        ushort* __restrict__ wcat) {
    int i = blockIdx.x * blockDim.x + threadIdx.x;
    if (i < 5 * 64 * 128) {
        int k = i & 127;
        int o = (i >> 7) & 63;
        int l = i >> 13;
        float v = (k < 64) ? rel_w[l * 4096 + o * 64 + k]
                           : root_w[l * 4096 + o * 64 + (k - 64)];
        wcat[i] = (ushort)bf16rne(v);
    }
}

// ---------------- aggregation v9b: bf16 gather, 16B requests, bf16 out ----------------
// one wave per node; lanes = 8 edge-groups x 8 channel-octs (16 B uint4).
// Compulsory-broadcast L3-service-bound (~35 us/layer): insensitive to
// bytes (R16), requests (R19/20), blocking (R13-15), MSHR depth (R22).
// Structure frozen.
__global__ void aggregate_b_k(const ushort* __restrict__ hb, const int* __restrict__ start,
                              const int* __restrict__ deg, const int* __restrict__ col,
                              ushort* __restrict__ aggb) {
    int w = (blockIdx.x * blockDim.x + threadIdx.x) >> 6;
    int lane = threadIdx.x & 63;
    if (w >= NN) return;
    int eg = lane >> 3;   // edge group 0..7
    int oc = lane & 7;    // channel oct: ch 8oc..8oc+7
    int s = start[w], d = deg[w];
    float4 acc0 = make_float4(0.f, 0.f, 0.f, 0.f);   // ch 8oc+0..3
    float4 acc1 = make_float4(0.f, 0.f, 0.f, 0.f);   // ch 8oc+4..7
    const uint4* h4b = (const uint4*)hb;   // row stride = 8 uint4 = 128 B
    for (int base = 0; base < d; base += 32) {
        int idx = base + (lane & 31);
        int cv = col[s + ((idx < d) ? idx : 0)];   // one load, 32 distinct addrs
        int cnt = d - base;                        // >0; wave-uniform
        uint4 v0, v1;
        {
            int n0 = __shfl(cv, eg + 0, 64);
            int n1 = __shfl(cv, eg + 8, 64);
            v0 = h4b[(size_t)n0 * 8 + oc];
            v1 = h4b[(size_t)n1 * 8 + oc];
        }
        uint4 v2, v3;
        bool hi = (cnt > 16);                      // wave-uniform branch
        if (hi) {
            int n2 = __shfl(cv, eg + 16, 64);
            int n3 = __shfl(cv, eg + 24, 64);
            v2 = h4b[(size_t)n2 * 8 + oc];
            v3 = h4b[(size_t)n3 * 8 + oc];
        }
        if (eg + 0 < cnt) accb8(acc0, acc1, v0);
        if (eg + 8 < cnt) accb8(acc0, acc1, v1);
        if (hi) {
            if (eg + 16 < cnt) accb8(acc0, acc1, v2);
            if (eg + 24 < cnt) accb8(acc0, acc1, v3);
        }
    }
    // reduce over 8 edge groups (eg = lane bits 3..5): xor 8,16,32
#pragma unroll
    for (int off = 8; off <= 32; off <<= 1) {
        acc0.x += __shfl_xor(acc0.x, off, 64);
        acc0.y += __shfl_xor(acc0.y, off, 64);
        acc0.z += __shfl_xor(acc0.z, off, 64);
        acc0.w += __shfl_xor(acc0.w, off, 64);
        acc1.x += __shfl_xor(acc1.x, off, 64);
        acc1.y += __shfl_xor(acc1.y, off, 64);
        acc1.z += __shfl_xor(acc1.z, off, 64);
        acc1.w += __shfl_xor(acc1.w, off, 64);
    }
    if (eg == 0) {   // lanes 0..7: oc-th 16 B (8 bf16) of the row
        uint4 wv;
        wv.x = bf16rne(acc0.x) | (bf16rne(acc0.y) << 16);
        wv.y = bf16rne(acc0.z) | (bf16rne(acc0.w) << 16);
        wv.z = bf16rne(acc1.x) | (bf16rne(acc1.y) << 16);
        wv.w = bf16rne(acc1.z) | (bf16rne(acc1.w) << 16);
        ((uint4*)(aggb + (size_t)w * DD))[oc] = wv;
    }
}

// ---------------- dense layer v6: MFMA bf16 GEMM (proven R21) ----------------
// C[64 nodes][64 out] = X[64][128] @ wcat_l^T, X = [aggb | hbin] bf16.
// block = 256 = 4 waves; wave wr owns 16-node slab, loops 4 out-tiles x
// 4 K-steps of mfma_f32_16x16x32_bf16. Frags (16x16x32): A lane holds
// A[lane&15][8*(lane>>4)+j]; B lane holds B[8*(lane>>4)+j][lane&15] =
// Wrow[lane&15][k..]; C/D col=lane&15, row=4*(lane>>4)+reg (m89).
// Epilogue via LDS [64][68]: bias + (RESID: + bf16 hbin) + relu ->
// bf16 out (uint2); fp32 out only when LAST (pool input).
// Buffers padded +64 rows: last block (16 valid rows) frag-loads OOB rows
// harmlessly (C rows never written past nrows).
template <int RESID, int LAST>
__global__ void __launch_bounds__(256, 4)
dense_mfma_k(const ushort* __restrict__ aggb, const ushort* __restrict__ hbin,
             const ushort* __restrict__ wcat, const float* __restrict__ brel,
             ushort* __restrict__ hbout, float* __restrict__ houtf) {
    __shared__ float Cs[64][68];
    const int t = threadIdx.x;
    const int lane = t & 63;
    const int wr = t >> 6;            // wave id = node-slab 0..3
    const int tile = blockIdx.x * 64;
    const int nrows = min(64, NN - tile);

    const int r16 = lane & 15;        // A row in slab / B out-col in tile
    const int kg = lane >> 4;         // k-group 0..3 (8 contiguous k)

    const size_t node = (size_t)(tile + wr * 16 + r16);   // may pad-read past NN
    bf16x8 a0 = *(const bf16x8*)(aggb + node * DD +  0 + kg * 8);
    bf16x8 a1 = *(const bf16x8*)(aggb + node * DD + 32 + kg * 8);
    bf16x8 a2 = *(const bf16x8*)(hbin + node * DD +  0 + kg * 8);
    bf16x8 a3 = *(const bf16x8*)(hbin + node * DD + 32 + kg * 8);

#pragma unroll
    for (int oc = 0; oc < 4; ++oc) {
        const ushort* wrow = wcat + (size_t)(oc * 16 + r16) * 128 + kg * 8;
        bf16x8 b0 = *(const bf16x8*)(wrow + 0);
        bf16x8 b1 = *(const bf16x8*)(wrow + 32);
        bf16x8 b2 = *(const bf16x8*)(wrow + 64);
        bf16x8 b3 = *(const bf16x8*)(wrow + 96);
        f32x4 c = {0.f, 0.f, 0.f, 0.f};
        c = __builtin_amdgcn_mfma_f32_16x16x32_bf16(a0, b0, c, 0, 0, 0);
        c = __builtin_amdgcn_mfma_f32_16x16x32_bf16(a1, b1, c, 0, 0, 0);
        c = __builtin_amdgcn_mfma_f32_16x16x32_bf16(a2, b2, c, 0, 0, 0);
        c = __builtin_amdgcn_mfma_f32_16x16x32_bf16(a3, b3, c, 0, 0, 0);
        float bias = brel[oc * 16 + r16];
#pragma unroll
        for (int r = 0; r < 4; ++r)
            Cs[wr * 16 + kg * 4 + r][oc * 16 + r16] = c[r] + bias;
    }
    __syncthreads();

    const uint2* hbin2 = (const uint2*)hbin + (size_t)tile * 16;   // row = 16 uint2
    uint2* outb2 = (uint2*)hbout + (size_t)tile * 16;
    float4* out4 = (float4*)(houtf + (size_t)tile * DD);
#pragma unroll
    for (int k = 0; k < 4; ++k) {
        int idx = t + k * 256;
        int row = idx >> 4, cq = idx & 15;
        if (row < nrows) {
            float4 r = *(const float4*)&Cs[row][4 * cq];
            if (RESID) {
                float4 hv = expb(hbin2[idx]);
                r.x += hv.x; r.y += hv.y; r.z += hv.z; r.w += hv.w;
            }
            r.x = fmaxf(r.x, 0.f); r.y = fmaxf(r.y, 0.f);
            r.z = fmaxf(r.z, 0.f); r.w = fmaxf(r.w, 0.f);
            uint2 wb;
            wb.x = bf16rne(r.x) | (bf16rne(r.y) << 16);
            wb.y = bf16rne(r.z) | (bf16rne(r.w) << 16);
            outb2[idx] = wb;
            if (LAST) out4[idx] = r;
        }
    }
}

// ---------------- pooling (batch is sorted) ----------------

__global__ void pool_k(const float* __restrict__ h, const int* __restrict__ batch,
                       float* __restrict__ sums, int* __restrict__ cnt) {
    const int NP = 32;
    int w = (blockIdx.x * blockDim.x + threadIdx.x) >> 6;
    int lane = threadIdx.x & 63;
    int n0 = w * NP;
    if (n0 >= NN) return;
    int n1 = min(n0 + NP, NN);
    int g = batch[n0];
    float acc = 0.f;
    int run = 0;
    for (int i = n0; i < n1; ++i) {
        int gi = batch[i];
        if (gi != g) {
            atomicAdd(&sums[g * DD + lane], acc);
            if (lane == 0) atomicAdd(&cnt[g], run);
            acc = 0.f; run = 0; g = gi;
        }
        acc += h[i * DD + lane];
        run++;
    }
    atomicAdd(&sums[g * DD + lane], acc);
    if (lane == 0) atomicAdd(&cnt[g], run);
}

// ---------------- head: mean -> linear -> softmax ----------------

__global__ void head_k(const float* __restrict__ sums, const int* __restrict__ cnt,
                       const float* __restrict__ lin_w, const float* __restrict__ lin_b,
                       float* __restrict__ out) {
    int g = blockIdx.x * (blockDim.x >> 6) + (threadIdx.x >> 6);
    int o = threadIdx.x & 63;
    if (g >= NG) return;
    float c = (float)cnt[g];
    float inv = 1.0f / fmaxf(c, 1.0f);
    float acc = lin_b[o];
#pragma unroll 8
    for (int k = 0; k < DD; ++k) {
        acc += sums[g * DD + k] * inv * lin_w[o * DD + k];
    }
    float m = acc;
#pragma unroll
    for (int off = 32; off; off >>= 1) m = fmaxf(m, __shfl_xor(m, off, 64));
    float e = __expf(acc - m);
    float s = e;
#pragma unroll
    for (int off = 32; off; off >>= 1) s += __shfl_xor(s, off, 64);
    out[g * DD + o] = e / s;
}

// ---------------- driver ----------------

extern "C" void kernel_launch(void* const* d_in, const int* in_sizes, int n_in,
                              void* d_out, int out_size, void* d_ws, size_t ws_size,
                              hipStream_t stream) {
    const float* x      = (const float*)d_in[0];
    const int*   edge   = (const int*)d_in[1];   // [2, E]: src = edge, dst = edge+NE
    const int*   batch  = (const int*)d_in[2];
    const float* rel_w  = (const float*)d_in[3]; // [L, D, D]
    const float* rel_b  = (const float*)d_in[4]; // [L, D]
    const float* root_w = (const float*)d_in[5]; // [L, D, D]
    const float* lin_w  = (const float*)d_in[6]; // [D, D]
    const float* lin_b  = (const float*)d_in[7]; // [D]
    float* out = (float*)d_out;

    const int* src = edge;
    const int* dst = edge + NE;

    // workspace carve (all 256B aligned)
    char* p = (char*)d_ws;
    auto carve = [&](size_t bytes) {
        char* r = p;
        p += (bytes + 255) & ~(size_t)255;
        return (void*)r;
    };
    const size_t PADROWS = 64;   // frag-load overrun guard for last block
    float*  hAf  = (float*)carve((size_t)NN * DD * 4);                    // fp32 final (pool)
    ushort* xb   = (ushort*)carve((size_t)(NN + PADROWS) * DD * 2);       // bf16 ping
    ushort* hb   = (ushort*)carve((size_t)(NN + PADROWS) * DD * 2);       // bf16 pong
    ushort* aggb = (ushort*)carve((size_t)(NN + PADROWS) * DD * 2);       // bf16 aggregate
    ushort* wcat = (ushort*)carve((size_t)5 * 64 * 128 * 2);              // bf16 weights
    int*    col  = (int*)carve((size_t)NBU * CAP * 4);   // 4.0 MB, bucket gaps unread
    int*    ebuf = (int*)carve((size_t)NBU * CAP * 4);   // 4.0 MB packed (src<<6)|dlow
    int*    strt = (int*)carve((size_t)NN * 4);
    int*    deg  = (int*)carve((size_t)NN * 4);
    // ---- contiguous zero region (single memset) ----
    char* zbase = p;
    float* sums = (float*)carve((size_t)NG * DD * 4);
    int*   cnt  = (int*)carve((size_t)NG * 4);
    int*   bcur = (int*)carve((size_t)NBU * 4);
    size_t zbytes = (size_t)(p - zbase);

    (void)hipMemsetAsync(zbase, 0, zbytes, stream);

    const int cvtBlocks = (NN * DD / 4 + 255) / 256;

    // conversions + CSR build v3
    to_bf16_k<<<cvtBlocks, 256, 0, stream>>>(x, xb);
    cvt_w_k<<<(5 * 64 * 128 + 255) / 256, 256, 0, stream>>>(rel_w, root_w, wcat);
    bucket_scatter_k<<<NBLK, 256, 0, stream>>>(src, dst, bcur, ebuf);
    bucket_finalize_k<<<NBU, 256, 0, stream>>>(ebuf, bcur, deg, strt, col);

    const int aggBlocks = (NN + 3) / 4;     // 4 waves (nodes) per block
    const int dnsBlocks = (NN + 63) / 64;   // 64 nodes per block

    // layer 0: gather xb -> aggb; mfma-dense -> hb
    aggregate_b_k<<<aggBlocks, 256, 0, stream>>>(xb, strt, deg, col, aggb);
    dense_mfma_k<0, 0><<<dnsBlocks, 256, 0, stream>>>(aggb, xb, wcat, rel_b, hb, hAf);
    // layer 1: gather hb -> aggb; dense -> xb
    aggregate_b_k<<<aggBlocks, 256, 0, stream>>>(hb, strt, deg, col, aggb);
    dense_mfma_k<0, 0><<<dnsBlocks, 256, 0, stream>>>(aggb, hb, wcat + 8192, rel_b + 64,
                                                      xb, hAf);
    // layer 2: gather xb; dense -> hb
    aggregate_b_k<<<aggBlocks, 256, 0, stream>>>(xb, strt, deg, col, aggb);
    dense_mfma_k<0, 0><<<dnsBlocks, 256, 0, stream>>>(aggb, xb, wcat + 2 * 8192,
                                                      rel_b + 2 * 64, hb, hAf);
    // layer 3 (residual): gather hb; dense -> xb
    aggregate_b_k<<<aggBlocks, 256, 0, stream>>>(hb, strt, deg, col, aggb);
    dense_mfma_k<1, 0><<<dnsBlocks, 256, 0, stream>>>(aggb, hb, wcat + 3 * 8192,
                                                      rel_b + 3 * 64, xb, hAf);
    // layer 4 (residual, LAST): gather xb; dense -> hb + fp32 hAf for pool
    aggregate_b_k<<<aggBlocks, 256, 0, stream>>>(xb, strt, deg, col, aggb);
    dense_mfma_k<1, 1><<<dnsBlocks, 256, 0, stream>>>(aggb, xb, wcat + 4 * 8192,
                                                      rel_b + 4 * 64, hb, hAf);

    // pool + head
    const int wavesPool = (NN + 31) / 32;
    pool_k<<<(wavesPool + 3) / 4, 256, 0, stream>>>(hAf, batch, sums, cnt);
    head_k<<<(NG + 3) / 4, 256, 0, stream>>>(sums, cnt, lin_w, lin_b, out);
}